// Round 4
// baseline (330.449 us; speedup 1.0000x reference)
//
#include <hip/hip_runtime.h>
#include <cstdint>
#include <cstddef>

// DenseCaps dynamic routing, MI355X. B=256, R=2048, NC=10, OUT=16, IN=8, 3 iters.
//
// R4 = R3 structure + race fix. R3 failed (absmax 0.876) because lanes
// n>=10 performed an UNMASKED 16-float RMW at sacc[.. + n*16] — past the
// 164-float row, trampling the neighboring group's row (and, at the wave
// edge, past the sacc allocation) in the same wave store instruction.
// Fix: guard the sacc RMW with n < NC_ (active writes end at float 159).
//
// Structure recap:
//  - u_hat NEVER materialized (materializing costs ~210us of HBM sweeps).
//    Recompute u = x.W per pass: W[r] fragment (128 floats) in VGPRs,
//    amortized over a 16-batch LDS tile of x (broadcast reads).
//  - Deferred logits: b_k = b_in + dot(u, v0+..+v_{k-1}) (verified R2),
//    so passes only communicate via the tiny s0..s3 buffers.
//  - Per-wave LDS s-partials (stride-164 rows, conflict-free b128 RMW),
//    one atomic flush per block into 2-way-spread global buffers.
//  - blockIdx = bgrp*32 + blkr => XCD = blkr%8: all 16 batch-groups that
//    share a W panel land on the same XCD L2.

#define B_   256
#define R_   2048
#define NC_  10

typedef __attribute__((ext_vector_type(4))) float f32x4;

__device__ __forceinline__ float rsum16(float x){
  x += __shfl_xor(x, 1, 16);
  x += __shfl_xor(x, 2, 16);
  x += __shfl_xor(x, 4, 16);
  x += __shfl_xor(x, 8, 16);
  return x;
}
__device__ __forceinline__ float rmax16(float x){
  x = fmaxf(x, __shfl_xor(x, 1, 16));
  x = fmaxf(x, __shfl_xor(x, 2, 16));
  x = fmaxf(x, __shfl_xor(x, 4, 16));
  x = fmaxf(x, __shfl_xor(x, 8, 16));
  return x;
}

// MODE 0: c = softmax(b_in)        -> s0 += c*u
// MODE k: vsum = sum_j<k squash(s_j); c = softmax(b_in + u.vsum) -> s_k += c*u
// MODE 3 additionally writes c to c_out.
template<int MODE>
__global__ __launch_bounds__(256, 2) void route_pass(
    const float* __restrict__ x,     // [256][2048][8]
    const float* __restrict__ W,     // [2048][8][160]
    const float* __restrict__ b_in,  // [2048][10]
    float*       __restrict__ c_out, // [256][2048][10]
    const float* __restrict__ s0,    // each s: [2][256][160] (2-way spread)
    const float* __restrict__ s1,
    const float* __restrict__ s2,
    float*       __restrict__ s_out)
{
  const int t    = threadIdx.x;
  const int blkr = blockIdx.x & 31;
  const int bgrp = blockIdx.x >> 5;
  const int b0   = bgrp * 16;
  const int n    = t & 15;
  const int grp  = t >> 4;          // 0..15: route-within-chunk
  const int w    = t >> 6;          // wave id 0..3
  const int nn   = (n < NC_) ? n : (NC_ - 1);

  __shared__ float xs[16 * 128];        // [bb][rr][i]  8 KB
  __shared__ float vs[16 * 164];        // [bloc][n*16+o], stride 164  10.5 KB
  __shared__ float sacc[4 * 16 * 164];  // per-wave s-partials  42 KB

  for (int idx = t; idx < 4 * 16 * 164; idx += 256) sacc[idx] = 0.f;

  if (MODE >= 1 && n < NC_){
    // stage vsum = sum_j squash(s_j[b]) for this block's 16 b's
    const int bloc = grp;
    const float* sl[3] = {s0, s1, s2};
    float vr[16];
    #pragma unroll
    for (int o = 0; o < 16; ++o) vr[o] = 0.f;
    #pragma unroll
    for (int j = 0; j < MODE; ++j){
      const float* sp = sl[j] + (size_t)(b0 + bloc) * 160 + n * 16;
      float row[16]; float ssq = 0.f;
      #pragma unroll
      for (int o = 0; o < 16; ++o){
        float v2 = sp[o] + sp[40960 + o];       // merge 2-way spread
        row[o] = v2; ssq = fmaf(v2, v2, ssq);
      }
      float f = sqrtf(ssq) / (1.f + ssq + 1e-8f);
      #pragma unroll
      for (int o = 0; o < 16; ++o) vr[o] = fmaf(f, row[o], vr[o]);
    }
    #pragma unroll
    for (int o = 0; o < 16; ++o) vs[bloc * 164 + n * 16 + o] = vr[o];
  }

  for (int rc4 = 0; rc4 < 4; ++rc4){
    const int r0 = blkr * 64 + rc4 * 16;
    const int r  = r0 + grp;
    __syncthreads();                       // xs readers done / vs+sacc ready
    // stage x tile: [16 b][16 r][8] = 512 uint4, fully coalesced
    #pragma unroll
    for (int k = 0; k < 2; ++k){
      int f = k * 256 + t;
      int bb = f >> 5, inner = f & 31;
      ((uint4*)xs)[f] =
        ((const uint4*)(x + ((size_t)(b0 + bb) * R_ + r0) * 8))[inner];
    }
    __syncthreads();

    // W[r] fragment for this lane's class -> 32 float4 in VGPRs
    f32x4 w4[32];
    {
      const float* wp = W + (size_t)r * 1280 + nn * 16;
      #pragma unroll
      for (int i = 0; i < 8; ++i)
        #pragma unroll
        for (int q = 0; q < 4; ++q)
          w4[i * 4 + q] = *(const f32x4*)(wp + i * 160 + q * 4);
    }
    const float binr = b_in[r * NC_ + nn];
    float c0r = 0.f;
    if (MODE == 0){
      float bnew = (n < NC_) ? binr : -1e30f;
      float m = rmax16(bnew);
      float e = __expf(bnew - m);
      float sum = rsum16(e);
      c0r = e / sum;
    }

    for (int bi = 0; bi < 16; ++bi){
      const int bloc = (grp + bi) & 15;
      const f32x4* xp = (const f32x4*)(xs + bloc * 128 + grp * 8);
      f32x4 xa = xp[0], xb = xp[1];
      float xr[8] = {xa[0], xa[1], xa[2], xa[3], xb[0], xb[1], xb[2], xb[3]};
      float u[16];
      #pragma unroll
      for (int o = 0; o < 16; ++o) u[o] = 0.f;
      #pragma unroll
      for (int i = 0; i < 8; ++i)
        #pragma unroll
        for (int o = 0; o < 16; ++o)
          u[o] = fmaf(xr[i], w4[i * 4 + (o >> 2)][o & 3], u[o]);

      float c;
      if (MODE == 0){
        c = c0r;
      } else {
        const f32x4* vp = (const f32x4*)(vs + bloc * 164 + nn * 16);
        float t0 = 0.f, t1 = 0.f, t2 = 0.f, t3 = 0.f;   // 4 chains for ILP
        f32x4 v0 = vp[0], v1 = vp[1], v2 = vp[2], v3 = vp[3];
        #pragma unroll
        for (int j = 0; j < 4; ++j){
          t0 = fmaf(u[j],      v0[j], t0);
          t1 = fmaf(u[4 + j],  v1[j], t1);
          t2 = fmaf(u[8 + j],  v2[j], t2);
          t3 = fmaf(u[12 + j], v3[j], t3);
        }
        float td = (t0 + t1) + (t2 + t3);
        float bnew = (n < NC_) ? (binr + td) : -1e30f;
        float m = rmax16(bnew);
        float e = __expf(bnew - m);
        float sum = rsum16(e);
        c = e / sum;
        if (MODE == 3 && n < NC_)
          c_out[((size_t)(b0 + bloc) * R_ + r) * NC_ + n] = c;
      }
      // per-wave s-partial accumulate (b128 RMW, stride-164 rows).
      // MASKED to n < NC_: lane n writes floats n*16..n*16+15 of the row;
      // n>=10 would overrun into the neighboring group's row (R3 bug).
      if (n < NC_){
        f32x4* sp = (f32x4*)(sacc + w * 2624 + bloc * 164 + n * 16);
        #pragma unroll
        for (int q = 0; q < 4; ++q){
          f32x4 sv = sp[q];
          #pragma unroll
          for (int j = 0; j < 4; ++j) sv[j] = fmaf(c, u[4 * q + j], sv[j]);
          sp[q] = sv;
        }
      }
    }
  }
  __syncthreads();
  // flush: merge 4 wave-copies, one atomic per value (2-way spread buffers)
  {
    const int bloc = t >> 4, col = t & 15;
    float* dst = s_out + (blkr & 1) * 40960 + (size_t)(b0 + bloc) * 160 + col;
    #pragma unroll
    for (int nf = 0; nf < NC_; ++nf){
      float acc = 0.f;
      #pragma unroll
      for (int ww = 0; ww < 4; ++ww)
        acc += sacc[ww * 2624 + bloc * 164 + nf * 16 + col];
      atomicAdd(dst + nf * 16, acc);
    }
  }
}

// ---------- final squash: v_out = squash(s3) (merging 2-way spread) ----------
__global__ __launch_bounds__(256) void squash_final(const float* __restrict__ s,
                                                    float* __restrict__ vout){
  int g = blockIdx.x * 256 + threadIdx.x;   // 16 lanes per (b,n) row
  float xv = s[g] + s[40960 + g];
  float ss = rsum16(xv * xv);
  float norm = sqrtf(ss);
  vout[g] = (norm / (1.f + ss + 1e-8f)) * xv;
}

extern "C" void kernel_launch(void* const* d_in, const int* in_sizes, int n_in,
                              void* d_out, int out_size, void* d_ws, size_t ws_size,
                              hipStream_t stream){
  const float* x    = (const float*)d_in[0];   // [256,2048,8]
  const float* W    = (const float*)d_in[1];   // [2048,8,160]
  const float* b_in = (const float*)d_in[2];   // [2048,10]
  float* out = (float*)d_out;
  float* out_v = out;                 // 40960 floats
  float* c_out = out + 40960;         // [B][R][NC] final coupling coeffs

  float* s0 = (float*)d_ws;           // 4 buffers x 2 spread-halves x 160KB
  float* s1 = s0 + 2 * 40960;
  float* s2 = s1 + 2 * 40960;
  float* s3 = s2 + 2 * 40960;

  hipMemsetAsync(s0, 0, 8 * 40960 * sizeof(float), stream);
  route_pass<0><<<512, 256, 0, stream>>>(x, W, b_in, c_out, s0, s1, s2, s0);
  route_pass<1><<<512, 256, 0, stream>>>(x, W, b_in, c_out, s0, s1, s2, s1);
  route_pass<2><<<512, 256, 0, stream>>>(x, W, b_in, c_out, s0, s1, s2, s2);
  route_pass<3><<<512, 256, 0, stream>>>(x, W, b_in, c_out, s0, s1, s2, s3);
  squash_final<<<160, 256, 0, stream>>>(s3, out_v);
}